// Round 1
// baseline (410.088 us; speedup 1.0000x reference)
//
#include <hip/hip_runtime.h>
#include <hip/hip_bf16.h>
#include <cstdint>

#define N_NODES  262144
#define N_GRAPHS 1024
#define FEAT     256

using short8 = __attribute__((ext_vector_type(8))) short;
using f32x4  = __attribute__((ext_vector_type(4))) float;

#define MFMA_BF16 __builtin_amdgcn_mfma_f32_16x16x32_bf16

__device__ __forceinline__ unsigned short f2bf(float f){
    unsigned u = __float_as_uint(f);
    u = u + 0x7FFFu + ((u >> 16) & 1u);   // round-to-nearest-even
    return (unsigned short)(u >> 16);
}
__device__ __forceinline__ float sigmoidf_(float x){ return 1.0f/(1.0f+__expf(-x)); }

// ---------------------------------------------------------------------------
// Kernel 1: per-graph logit part: glog[g] = dot(relu(g_feats[g]), logit_w[0:256]) + logit_b
// one wave per graph
__global__ __launch_bounds__(256) void glogit_kernel(
        const float* __restrict__ gf, const float* __restrict__ lw,
        const float* __restrict__ lb, float* __restrict__ glog){
    int wid  = (blockIdx.x*blockDim.x + threadIdx.x) >> 6;
    int lane = threadIdx.x & 63;
    if (wid >= N_GRAPHS) return;
    float4 g = ((const float4*)gf)[wid*64 + lane];
    float4 w = ((const float4*)lw)[lane];
    float p = fmaxf(g.x,0.f)*w.x + fmaxf(g.y,0.f)*w.y +
              fmaxf(g.z,0.f)*w.z + fmaxf(g.w,0.f)*w.w;
    #pragma unroll
    for (int m=1;m<64;m<<=1) p += __shfl_xor(p, m, 64);
    if (lane==0) glog[wid] = p + lb[0];
}

// ---------------------------------------------------------------------------
// Kernel 2: f32 -> bf16 conversions of g_feats, proj_w, w_ih, w_hh (vec4)
__global__ __launch_bounds__(256) void convert_kernel(
        const float* __restrict__ gf,  const float* __restrict__ pw,
        const float* __restrict__ wih, const float* __restrict__ whh,
        unsigned short* __restrict__ h_bf,  unsigned short* __restrict__ pw_bf,
        unsigned short* __restrict__ wih_bf, unsigned short* __restrict__ whh_bf){
    int i = blockIdx.x*blockDim.x + threadIdx.x;  // float4 index, total 180224
    const float* src; unsigned short* dst; int base;
    if      (i <  65536){ src=gf;  dst=h_bf;   base=i;        }
    else if (i <  81920){ src=pw;  dst=pw_bf;  base=i-65536;  }
    else if (i < 131072){ src=wih; dst=wih_bf; base=i-81920;  }
    else                { src=whh; dst=whh_bf; base=i-131072; }
    float4 v = ((const float4*)src)[base];
    ushort4 o; o.x=f2bf(v.x); o.y=f2bf(v.y); o.z=f2bf(v.z); o.w=f2bf(v.w);
    ((ushort4*)dst)[base] = o;
}

// ---------------------------------------------------------------------------
// Kernel 3: single pass over node_feats.
// wave-per-node: logit dot -> e=exp(leaky(glog+dot)) -> accumulate e*x and e
// per running segment in registers, atomic flush on segment change.
__global__ __launch_bounds__(256) void pass1_kernel(
        const float* __restrict__ nf, const int* __restrict__ seg,
        const float* __restrict__ glog, const float* __restrict__ lw1,
        float* __restrict__ num, float* __restrict__ den){
    const int NPW = 32;                       // nodes per wave (8192 waves)
    int wid  = (blockIdx.x*blockDim.x + threadIdx.x) >> 6;
    int lane = threadIdx.x & 63;
    int n0   = wid * NPW;
    float4 w4 = ((const float4*)lw1)[lane];   // logit_w[256 + 4*lane ..]
    const float4* nf4 = (const float4*)nf;

    float a0=0.f,a1=0.f,a2=0.f,a3=0.f,dacc=0.f;
    int   cur = seg[n0];
    float gl  = glog[cur];
    float4 x  = nf4[(size_t)n0*64 + lane];    // prefetch node 0
    int    s  = cur;

    for (int i=0;i<NPW;i++){
        float4 xc = x; int sc = s;
        if (i+1 < NPW){                       // software prefetch next node
            x = nf4[(size_t)(n0+i+1)*64 + lane];
            s = seg[n0+i+1];
        }
        if (sc != cur){                       // wave-uniform flush
            atomicAdd(&num[cur*FEAT + lane*4+0], a0);
            atomicAdd(&num[cur*FEAT + lane*4+1], a1);
            atomicAdd(&num[cur*FEAT + lane*4+2], a2);
            atomicAdd(&num[cur*FEAT + lane*4+3], a3);
            if (lane==0) atomicAdd(&den[cur], dacc);
            a0=a1=a2=a3=0.f; dacc=0.f; cur=sc; gl=glog[sc];
        }
        float p = xc.x*w4.x + xc.y*w4.y + xc.z*w4.z + xc.w*w4.w;
        #pragma unroll
        for (int m=1;m<64;m<<=1) p += __shfl_xor(p, m, 64);
        float q  = gl + p;
        float zf = q > 0.f ? q : 0.01f*q;     // leaky_relu
        float e  = __expf(zf);                // softmax without max-shift (safe: zf <~ 5)
        a0 += e*xc.x; a1 += e*xc.y; a2 += e*xc.z; a3 += e*xc.w;
        if (lane==0) dacc += e;
    }
    atomicAdd(&num[cur*FEAT + lane*4+0], a0);
    atomicAdd(&num[cur*FEAT + lane*4+1], a1);
    atomicAdd(&num[cur*FEAT + lane*4+2], a2);
    atomicAdd(&num[cur*FEAT + lane*4+3], a3);
    if (lane==0) atomicAdd(&den[cur], dacc);
}

// ---------------------------------------------------------------------------
// Kernel 4: g_repr = (num/den) @ proj_w^T + proj_b ; x_bf = bf16(elu(g_repr))
// one wave per 16x16 output tile; MFMA 16x16x32 bf16; fragments direct from L2.
// A-frag: lane holds A[rtile + (l&15)][kk + (l>>4)*8 + j]; B row-major = proj_w[n][k].
__global__ __launch_bounds__(256) void gemm1_kernel(
        const float* __restrict__ num, const float* __restrict__ den,
        const unsigned short* __restrict__ pw_bf, const float* __restrict__ pb,
        unsigned short* __restrict__ x_bf){
    int wid  = (blockIdx.x*blockDim.x + threadIdx.x) >> 6;  // 0..1023
    int lane = threadIdx.x & 63;
    int rtile = (wid >> 4) * 16;            // 64 row tiles
    int ctile = (wid & 15) * 16;            // 16 col tiles
    int arow = rtile + (lane & 15);
    int brow = ctile + (lane & 15);
    int kgrp = (lane >> 4) * 8;
    float dv  = den[arow];
    float inv = dv > 0.f ? 1.0f/dv : 0.f;
    f32x4 acc = {0.f,0.f,0.f,0.f};
    #pragma unroll
    for (int kk=0; kk<FEAT; kk+=32){
        int kb = kk + kgrp;
        float4 u0 = *(const float4*)(num + arow*FEAT + kb);
        float4 u1 = *(const float4*)(num + arow*FEAT + kb + 4);
        short8 af;
        af[0]=(short)f2bf(u0.x*inv); af[1]=(short)f2bf(u0.y*inv);
        af[2]=(short)f2bf(u0.z*inv); af[3]=(short)f2bf(u0.w*inv);
        af[4]=(short)f2bf(u1.x*inv); af[5]=(short)f2bf(u1.y*inv);
        af[6]=(short)f2bf(u1.z*inv); af[7]=(short)f2bf(u1.w*inv);
        short8 bfr = *(const short8*)(pw_bf + brow*FEAT + kb);
        acc = MFMA_BF16(af, bfr, acc, 0, 0, 0);
    }
    #pragma unroll
    for (int r=0;r<4;r++){
        int row = rtile + (lane>>4)*4 + r;  // C/D: col=lane&15, row=(lane>>4)*4+reg
        int col = ctile + (lane & 15);
        float g  = acc[r] + pb[col];
        float xv = g > 0.f ? g : (__expf(g) - 1.0f);   // elu
        x_bf[row*FEAT + col] = f2bf(xv);
    }
}

// ---------------------------------------------------------------------------
// Kernel 5: fused GRU: gi = x@w_ih^T+b_ih, gh = h@w_hh^T+b_hh, gates, output.
// one wave per 16x16 tile of the 1024x256 output; 6 accumulators (r/z/n × i/h).
__global__ __launch_bounds__(256) void gemm2_kernel(
        const unsigned short* __restrict__ x_bf, const unsigned short* __restrict__ h_bf,
        const unsigned short* __restrict__ wih_bf, const unsigned short* __restrict__ whh_bf,
        const float* __restrict__ bih, const float* __restrict__ bhh,
        const float* __restrict__ gf, float* __restrict__ out){
    int wid  = (blockIdx.x*blockDim.x + threadIdx.x) >> 6;  // 0..1023
    int lane = threadIdx.x & 63;
    int rtile = (wid >> 4) * 16;
    int ctile = (wid & 15) * 16;
    int arow = rtile + (lane & 15);
    int wrow = ctile + (lane & 15);         // W row for gate 0 (r)
    int kgrp = (lane >> 4) * 8;
    f32x4 ir={0,0,0,0}, iz={0,0,0,0}, inn={0,0,0,0};
    f32x4 hr={0,0,0,0}, hz={0,0,0,0}, hnn={0,0,0,0};
    #pragma unroll
    for (int kk=0; kk<FEAT; kk+=32){
        int kb = kk + kgrp;
        short8 ax  = *(const short8*)(x_bf  + arow*FEAT + kb);
        short8 ah  = *(const short8*)(h_bf  + arow*FEAT + kb);
        short8 bir = *(const short8*)(wih_bf + (wrow      )*FEAT + kb);
        short8 biz = *(const short8*)(wih_bf + (wrow + 256)*FEAT + kb);
        short8 bin = *(const short8*)(wih_bf + (wrow + 512)*FEAT + kb);
        short8 bhr = *(const short8*)(whh_bf + (wrow      )*FEAT + kb);
        short8 bhz = *(const short8*)(whh_bf + (wrow + 256)*FEAT + kb);
        short8 bhn = *(const short8*)(whh_bf + (wrow + 512)*FEAT + kb);
        ir  = MFMA_BF16(ax, bir, ir , 0,0,0);
        iz  = MFMA_BF16(ax, biz, iz , 0,0,0);
        inn = MFMA_BF16(ax, bin, inn, 0,0,0);
        hr  = MFMA_BF16(ah, bhr, hr , 0,0,0);
        hz  = MFMA_BF16(ah, bhz, hz , 0,0,0);
        hnn = MFMA_BF16(ah, bhn, hnn, 0,0,0);
    }
    #pragma unroll
    for (int r=0;r<4;r++){
        int row = rtile + (lane>>4)*4 + r;
        int col = ctile + (lane & 15);
        float vir = ir [r] + bih[col      ];
        float viz = iz [r] + bih[col + 256];
        float vin = inn[r] + bih[col + 512];
        float vhr = hr [r] + bhh[col      ];
        float vhz = hz [r] + bhh[col + 256];
        float vhn = hnn[r] + bhh[col + 512];
        float rg = sigmoidf_(vir + vhr);
        float zg = sigmoidf_(viz + vhz);
        float ng = tanhf(vin + rg*vhn);
        float h  = gf[row*FEAT + col];
        out[row*FEAT + col] = (1.f - zg)*ng + zg*h;
    }
}

// ---------------------------------------------------------------------------
extern "C" void kernel_launch(void* const* d_in, const int* in_sizes, int n_in,
                              void* d_out, int out_size, void* d_ws, size_t ws_size,
                              hipStream_t stream){
    const float* nf  = (const float*)d_in[0];
    const float* gf  = (const float*)d_in[1];
    const int*   seg = (const int*)  d_in[2];
    const float* lw  = (const float*)d_in[4];   // (1, 512)
    const float* lb  = (const float*)d_in[5];
    const float* pw  = (const float*)d_in[6];   // (256,256)
    const float* pb  = (const float*)d_in[7];
    const float* wih = (const float*)d_in[8];   // (768,256)
    const float* whh = (const float*)d_in[9];
    const float* bih = (const float*)d_in[10];
    const float* bhh = (const float*)d_in[11];
    float* out = (float*)d_out;

    // workspace layout (~3 MB total)
    float* num  = (float*)d_ws;                 // 1024*256
    float* den  = num + N_GRAPHS*FEAT;          // 1024
    float* glog = den + N_GRAPHS;               // 1024
    unsigned short* h_bf   = (unsigned short*)(glog + N_GRAPHS);
    unsigned short* pw_bf  = h_bf   + N_GRAPHS*FEAT;
    unsigned short* wih_bf = pw_bf  + FEAT*FEAT;
    unsigned short* whh_bf = wih_bf + 3*FEAT*FEAT;
    unsigned short* x_bf   = whh_bf + 3*FEAT*FEAT;

    hipMemsetAsync(d_ws, 0, (size_t)(N_GRAPHS*FEAT + N_GRAPHS)*sizeof(float), stream);
    glogit_kernel <<<N_GRAPHS/4, 256, 0, stream>>>(gf, lw, lb, glog);
    convert_kernel<<<704,        256, 0, stream>>>(gf, pw, wih, whh, h_bf, pw_bf, wih_bf, whh_bf);
    pass1_kernel  <<<2048,       256, 0, stream>>>(nf, seg, glog, lw + FEAT, num, den);
    gemm1_kernel  <<<256,        256, 0, stream>>>(num, den, pw_bf, pb, x_bf);
    gemm2_kernel  <<<256,        256, 0, stream>>>(x_bf, h_bf, wih_bf, whh_bf, bih, bhh, gf, out);
}